// Round 24
// baseline (106.152 us; speedup 1.0000x reference)
//
#include <hip/hip_runtime.h>
#include <hip/hip_bf16.h>
#include <hip/hip_fp8.h>
#include <stdint.h>

#define B_ROWS 8192
#define D_DIM  128
#define NSLAB  8               // 8 column ranges of 1024 cols
#define STEPS  8               // 128-col steps per block
#define NRB    64              // row-tiles

// zn8 rows are l2-normalized, scaled by SCALE = sqrt(2*log2(e)), quantized to
// fp8 e4m3. MFMA dot = 2*log2(e)*cos = log2(e^sim), sim = cos/tau, tau=0.5.
// exp2(acc) = e^sim <= e^2 (fp32-safe); pos = acc*ln2. (Validated R11-R23.)
#define SCALE  1.6986436f
#define LN2    0.69314718f

typedef __attribute__((ext_vector_type(2))) int   i32x2;
typedef __attribute__((ext_vector_type(4))) int   i32x4;
typedef __attribute__((ext_vector_type(4))) float f32x4;

typedef __attribute__((address_space(3))) uint32_t lds_u32;
typedef __attribute__((address_space(1))) const uint32_t glb_u32;

__device__ __forceinline__ float fast_exp2(float x) {
    float r;
    asm("v_exp_f32 %0, %1" : "=v"(r) : "v"(x));
    return r;
}
__device__ __forceinline__ float fast_log2(float x) {
    float r;
    asm("v_log_f32 %0, %1" : "=v"(r) : "v"(x));
    return r;
}

__device__ __forceinline__ long half64(i32x4 v, int h) {
    i32x2 p;
    p.x = h ? v.z : v.x;
    p.y = h ? v.w : v.y;
    return __builtin_bit_cast(long, p);
}

// ---------------- Kernel 1: l2-normalize rows, scale, quantize to fp8 -------
// Block 0 also zeroes the 64 per-rb arrival counters + the final counter
// (per-launch reset; stream ordering guarantees visibility to k_sim).
__global__ void k_norm(const float* __restrict__ z, uint8_t* __restrict__ zn8,
                       unsigned* __restrict__ cnt) {
    if (blockIdx.x == 0 && threadIdx.x < NRB + 1) cnt[threadIdx.x] = 0;
    int row  = blockIdx.x * 4 + (threadIdx.x >> 6);
    int lane = threadIdx.x & 63;
    const float2 v = reinterpret_cast<const float2*>(z + (size_t)row * D_DIM)[lane];
    float ss = v.x * v.x + v.y * v.y;
    #pragma unroll
    for (int m = 1; m < 64; m <<= 1) ss += __shfl_xor(ss, m);
    float inv = SCALE * rsqrtf(fmaxf(ss, 1e-12f));
    __hip_fp8_e4m3 qx(v.x * inv);
    __hip_fp8_e4m3 qy(v.y * inv);
    unsigned short u = (unsigned short)qx.__x | ((unsigned short)qy.__x << 8);
    reinterpret_cast<unsigned short*>(zn8 + (size_t)row * D_DIM)[lane] = u;
}

// ---------------- Kernel 2: fp8 similarity + fully fused loss ---------------
// Hot loop byte-identical to the R20/R22/R23 champion. NEW: the loss
// reduction is fused via the R23-validated arrival-counter idiom, one level
// deeper — the LAST of the 8 cr-blocks per row-tile computes that tile's 128
// row-losses (slab reads L2-hot, fixed-order -> deterministic) and the last
// rb overall does the fixed-order 64-way final sum. No k_loss dispatch.
__global__ __launch_bounds__(512, 4) void k_sim(const uint8_t* __restrict__ zn8,
                                                float* __restrict__ s_partial,
                                                float* __restrict__ pos,
                                                float* __restrict__ part_rb,
                                                unsigned* __restrict__ cnt,
                                                float* __restrict__ out) {
    __shared__ __align__(16) char sB[2][16384];
    __shared__ float red[128][2];

    const int tid  = threadIdx.x;
    const int lane = tid & 63;
    const int l15  = lane & 15;
    const int lg   = lane >> 4;          // 0..3
    const int w    = tid >> 6;           // 0..7
    const int wr   = w >> 1;             // 0..3 : rows [wr*32, +32)
    const int wc   = w & 1;              // 0..1 : cols [wc*64, +64) within step
    const int rb   = blockIdx.x >> 3;    // 0..63  (128-row tile)
    const int cr   = blockIdx.x & 7;     // 0..7   (1024-col range)
    const int R0   = rb * 128;
    const int C0   = cr * 1024;

    // stage one 128-col fp8 tile (16 KB): 2x 16B per thread, linear LDS dest,
    // inverse-XOR global source (involution u ^= col&7 on the 8 16B units)
    auto stage = [&](int gColBase, char* dst) {
        #pragma unroll
        for (int q = 0; q < 2; ++q) {
            int unit = q * 512 + tid;        // 0..1023
            int col  = unit >> 3;            // 0..127
            int u    = unit & 7;
            const uint8_t* g = zn8 + (size_t)(gColBase + col) * D_DIM
                                   + ((u ^ (col & 7)) << 4);
            __builtin_amdgcn_global_load_lds((glb_u32*)g, (lds_u32*)(dst + unit * 16), 16, 0, 0);
        }
    };

    stage(C0, sB[0]);                    // first tile in flight

    // ---- A fragments: global -> registers (2t x 2kp x 16B = 16 VGPR)
    i32x4 afr[2][2];
    #pragma unroll
    for (int t = 0; t < 2; ++t)
        #pragma unroll
        for (int kp = 0; kp < 2; ++kp) {
            int row = R0 + wr * 32 + t * 16 + l15;
            afr[t][kp] = *reinterpret_cast<const i32x4*>(
                zn8 + (size_t)row * D_DIM + kp * 64 + lg * 16);
        }

    float srow[2][4];
    #pragma unroll
    for (int t = 0; t < 2; ++t)
        #pragma unroll
        for (int r = 0; r < 4; ++r) srow[t][r] = 0.f;

    __syncthreads();                     // tile 0 + A loads landed

    #pragma unroll 1
    for (int s = 0; s < STEPS; ++s) {
        if (s + 1 < STEPS)
            stage(C0 + (s + 1) * 128, sB[(s + 1) & 1]);   // prefetch next

        const char* bb = sB[s & 1];
        i32x4 bfr[4][2];
        #pragma unroll
        for (int cs = 0; cs < 4; ++cs)
            #pragma unroll
            for (int kp = 0; kp < 2; ++kp) {
                int c = wc * 64 + cs * 16 + l15;
                bfr[cs][kp] = *reinterpret_cast<const i32x4*>(
                    bb + c * 128 + (((kp * 4 + lg) ^ (c & 7)) << 4));
            }

        #pragma unroll
        for (int t = 0; t < 2; ++t)
            #pragma unroll
            for (int cs = 0; cs < 4; ++cs) {
                f32x4 acc = {0.f, 0.f, 0.f, 0.f};
                #pragma unroll
                for (int kp = 0; kp < 2; ++kp)
                    #pragma unroll
                    for (int h = 0; h < 2; ++h)
                        acc = __builtin_amdgcn_mfma_f32_16x16x32_fp8_fp8(
                                half64(afr[t][kp], h), half64(bfr[cs][kp], h),
                                acc, 0, 0, 0);

                const int fragRow = R0 + wr * 32 + t * 16;
                const int fragCol = C0 + s * 128 + wc * 64 + cs * 16;
                if (fragRow == fragCol) {        // diagonal frag (wave-uniform)
                    const int col = fragCol + l15;
                    #pragma unroll
                    for (int r = 0; r < 4; ++r) {
                        int row = fragRow + lg * 4 + r;
                        float e = fast_exp2(acc[r]);                     // e^sim
                        if (col == row) e = 0.f;                         // self
                        if (col == (row ^ 1)) pos[row] = acc[r] * LN2;   // partner
                        srow[t][r] += e;
                    }
                } else {
                    #pragma unroll
                    for (int r = 0; r < 4; ++r)
                        srow[t][r] += fast_exp2(acc[r]);
                }
            }
        __syncthreads();   // prefetched tile landed; current buffer reusable
    }

    // ---- reduction: 16 lanes sharing a row -> cross-wave (wc) via LDS
    #pragma unroll
    for (int t = 0; t < 2; ++t)
        #pragma unroll
        for (int r = 0; r < 4; ++r) {
            float v = srow[t][r];
            v += __shfl_xor(v, 1);
            v += __shfl_xor(v, 2);
            v += __shfl_xor(v, 4);
            v += __shfl_xor(v, 8);
            if (l15 == 0) red[wr * 32 + t * 16 + lg * 4 + r][wc] = v;
        }
    __syncthreads();
    if (tid < 128)
        s_partial[(size_t)cr * B_ROWS + R0 + tid] = red[tid][0] + red[tid][1];

    // ---- fused loss: last-of-8 cr-blocks per rb computes this tile's loss
    __threadfence();                    // release own s_partial/pos stores
    __syncthreads();                    // all fences done before the signal
    __shared__ unsigned arrival;
    __shared__ bool fin;
    if (tid == 0) arrival = atomicAdd(&cnt[rb], 1u);
    __syncthreads();
    if (arrival == NSLAB - 1) {         // block-uniform: last for this rb
        __threadfence();                // acquire: all 8 slabs + pos visible
        float v = 0.f;
        if (tid < 128) {
            int row = R0 + tid;
            float ssum = 0.f;
            #pragma unroll
            for (int c = 0; c < NSLAB; ++c) ssum += s_partial[(size_t)c * B_ROWS + row];
            v = LN2 * fast_log2(ssum) - pos[row];
        }
        #pragma unroll
        for (int m = 1; m < 64; m <<= 1) v += __shfl_xor(v, m);
        __shared__ float l2s[2];
        if (tid == 0)  l2s[0] = v;
        if (tid == 64) l2s[1] = v;
        __syncthreads();
        if (tid == 0) {
            atomicExch(part_rb + rb, l2s[0] + l2s[1]);   // coherence-point write
            __threadfence();                             // release
            fin = (atomicAdd(&cnt[NRB], 1u) == NRB - 1);
        }
        __syncthreads();
        if (fin) {                       // very last rb: final fixed-order sum
            __threadfence();             // acquire
            if (tid < 64) {
                float f = part_rb[tid];
                #pragma unroll
                for (int m = 1; m < 64; m <<= 1) f += __shfl_xor(f, m);
                if (tid == 0) out[0] = f * (1.0f / (float)B_ROWS);
            }
        }
    }
}

extern "C" void kernel_launch(void* const* d_in, const int* in_sizes, int n_in,
                              void* d_out, int out_size, void* d_ws, size_t ws_size,
                              hipStream_t stream) {
    const float* z = (const float*)d_in[0];
    float* out = (float*)d_out;

    char* ws = (char*)d_ws;
    uint8_t* zn8 = (uint8_t*)ws;                                           // 1 MB
    float* s_partial = (float*)(ws + (size_t)B_ROWS * D_DIM);              // 256 KB
    float* pos     = (float*)((char*)s_partial + (size_t)NSLAB * B_ROWS * 4); // 32 KB
    float* part_rb = (float*)((char*)pos + (size_t)B_ROWS * 4);            // 256 B
    unsigned* cnt  = (unsigned*)((char*)part_rb + NRB * 4);                // 260 B

    // 1) normalize + scale + fp8 quantize (+ counter reset)
    k_norm<<<B_ROWS / 4, 256, 0, stream>>>(z, zn8, cnt);

    // 2) fp8 similarity + fully fused loss: 512 blocks (2/CU)
    k_sim<<<64 * NSLAB, 512, 0, stream>>>(zn8, s_partial, pos, part_rb, cnt, out);
}

// Round 25
// 30.152 us; speedup vs baseline: 3.5206x; 3.5206x over previous
//
#include <hip/hip_runtime.h>
#include <hip/hip_bf16.h>
#include <hip/hip_fp8.h>
#include <stdint.h>

#define B_ROWS 8192
#define D_DIM  128
#define NSLAB  8               // 8 column ranges of 1024 cols
#define STEPS  8               // 128-col steps per block
#define NLOSS  32              // blocks in the fused loss kernel

// zn8 rows are l2-normalized, scaled by SCALE = sqrt(2*log2(e)), quantized to
// fp8 e4m3. MFMA dot = 2*log2(e)*cos = log2(e^sim), sim = cos/tau, tau=0.5.
// exp2(acc) = e^sim <= e^2 (fp32-safe); pos = acc*ln2. (Validated R11-R23.)
#define SCALE  1.6986436f
#define LN2    0.69314718f

typedef __attribute__((ext_vector_type(2))) int   i32x2;
typedef __attribute__((ext_vector_type(4))) int   i32x4;
typedef __attribute__((ext_vector_type(4))) float f32x4;

typedef __attribute__((address_space(3))) uint32_t lds_u32;
typedef __attribute__((address_space(1))) const uint32_t glb_u32;

__device__ __forceinline__ float fast_exp2(float x) {
    float r;
    asm("v_exp_f32 %0, %1" : "=v"(r) : "v"(x));
    return r;
}
__device__ __forceinline__ float fast_log2(float x) {
    float r;
    asm("v_log_f32 %0, %1" : "=v"(r) : "v"(x));
    return r;
}

__device__ __forceinline__ long half64(i32x4 v, int h) {
    i32x2 p;
    p.x = h ? v.z : v.x;
    p.y = h ? v.w : v.y;
    return __builtin_bit_cast(long, p);
}

// ---------------- Kernel 1: l2-normalize rows, scale, quantize to fp8 -------
// Block 0 also zeroes the loss kernel's arrival counter (per-launch reset;
// inter-kernel visibility on one stream is guaranteed).
__global__ void k_norm(const float* __restrict__ z, uint8_t* __restrict__ zn8,
                       unsigned* __restrict__ cnt) {
    if (blockIdx.x == 0 && threadIdx.x == 0) *cnt = 0;
    int row  = blockIdx.x * 4 + (threadIdx.x >> 6);
    int lane = threadIdx.x & 63;
    const float2 v = reinterpret_cast<const float2*>(z + (size_t)row * D_DIM)[lane];
    float ss = v.x * v.x + v.y * v.y;
    #pragma unroll
    for (int m = 1; m < 64; m <<= 1) ss += __shfl_xor(ss, m);
    float inv = SCALE * rsqrtf(fmaxf(ss, 1e-12f));
    __hip_fp8_e4m3 qx(v.x * inv);
    __hip_fp8_e4m3 qy(v.y * inv);
    unsigned short u = (unsigned short)qx.__x | ((unsigned short)qy.__x << 8);
    reinterpret_cast<unsigned short*>(zn8 + (size_t)row * D_DIM)[lane] = u;
}

// ---------------- Kernel 2: fp8 similarity + fused exp row-sums -------------
// CHAMPION (R20/R22/R23, 30.2 us total; best of 24 rounds).
// 512 blocks (2/CU), 512 thr = 8 waves (4 row-groups x 2 col-halves),
// 16 waves/CU. Wave = 32 rows x 64 cols/step; step = 128 cols (16 KB fp8
// tile) double-buffered in LDS; sync-per-step prefetch.
// MFMA = mfma_f32_16x16x32_fp8_fp8, K-chain 4. A and B use the IDENTICAL
// k-slot byte mapping (kp*64 + lg*16 + h*8) so k-permutations cancel.
__global__ __launch_bounds__(512, 4) void k_sim(const uint8_t* __restrict__ zn8,
                                                float* __restrict__ s_partial,
                                                float* __restrict__ pos) {
    __shared__ __align__(16) char sB[2][16384];
    __shared__ float red[128][2];

    const int tid  = threadIdx.x;
    const int lane = tid & 63;
    const int l15  = lane & 15;
    const int lg   = lane >> 4;          // 0..3
    const int w    = tid >> 6;           // 0..7
    const int wr   = w >> 1;             // 0..3 : rows [wr*32, +32)
    const int wc   = w & 1;              // 0..1 : cols [wc*64, +64) within step
    const int rb   = blockIdx.x >> 3;    // 0..63  (128-row tile)
    const int cr   = blockIdx.x & 7;     // 0..7   (1024-col range)
    const int R0   = rb * 128;
    const int C0   = cr * 1024;

    // stage one 128-col fp8 tile (16 KB): 2x 16B per thread, linear LDS dest,
    // inverse-XOR global source (involution u ^= col&7 on the 8 16B units)
    auto stage = [&](int gColBase, char* dst) {
        #pragma unroll
        for (int q = 0; q < 2; ++q) {
            int unit = q * 512 + tid;        // 0..1023
            int col  = unit >> 3;            // 0..127
            int u    = unit & 7;
            const uint8_t* g = zn8 + (size_t)(gColBase + col) * D_DIM
                                   + ((u ^ (col & 7)) << 4);
            __builtin_amdgcn_global_load_lds((glb_u32*)g, (lds_u32*)(dst + unit * 16), 16, 0, 0);
        }
    };

    stage(C0, sB[0]);                    // first tile in flight

    // ---- A fragments: global -> registers (2t x 2kp x 16B = 16 VGPR)
    // slot (kp,h): bytes kp*64 + lg*16 + h*8 of the row
    i32x4 afr[2][2];
    #pragma unroll
    for (int t = 0; t < 2; ++t)
        #pragma unroll
        for (int kp = 0; kp < 2; ++kp) {
            int row = R0 + wr * 32 + t * 16 + l15;
            afr[t][kp] = *reinterpret_cast<const i32x4*>(
                zn8 + (size_t)row * D_DIM + kp * 64 + lg * 16);
        }

    float srow[2][4];
    #pragma unroll
    for (int t = 0; t < 2; ++t)
        #pragma unroll
        for (int r = 0; r < 4; ++r) srow[t][r] = 0.f;

    __syncthreads();                     // tile 0 + A loads landed

    #pragma unroll 1
    for (int s = 0; s < STEPS; ++s) {
        if (s + 1 < STEPS)
            stage(C0 + (s + 1) * 128, sB[(s + 1) & 1]);   // prefetch next

        // B fragments: col c, unit g = kp*4+lg, swizzled b128 (2-way banks)
        const char* bb = sB[s & 1];
        i32x4 bfr[4][2];
        #pragma unroll
        for (int cs = 0; cs < 4; ++cs)
            #pragma unroll
            for (int kp = 0; kp < 2; ++kp) {
                int c = wc * 64 + cs * 16 + l15;
                bfr[cs][kp] = *reinterpret_cast<const i32x4*>(
                    bb + c * 128 + (((kp * 4 + lg) ^ (c & 7)) << 4));
            }

        #pragma unroll
        for (int t = 0; t < 2; ++t)
            #pragma unroll
            for (int cs = 0; cs < 4; ++cs) {
                f32x4 acc = {0.f, 0.f, 0.f, 0.f};
                #pragma unroll
                for (int kp = 0; kp < 2; ++kp)
                    #pragma unroll
                    for (int h = 0; h < 2; ++h)
                        acc = __builtin_amdgcn_mfma_f32_16x16x32_fp8_fp8(
                                half64(afr[t][kp], h), half64(bfr[cs][kp], h),
                                acc, 0, 0, 0);

                const int fragRow = R0 + wr * 32 + t * 16;
                const int fragCol = C0 + s * 128 + wc * 64 + cs * 16;
                if (fragRow == fragCol) {        // diagonal frag (wave-uniform)
                    const int col = fragCol + l15;
                    #pragma unroll
                    for (int r = 0; r < 4; ++r) {
                        int row = fragRow + lg * 4 + r;
                        float e = fast_exp2(acc[r]);                     // e^sim
                        if (col == row) e = 0.f;                         // self
                        if (col == (row ^ 1)) pos[row] = acc[r] * LN2;   // partner
                        srow[t][r] += e;
                    }
                } else {
                    #pragma unroll
                    for (int r = 0; r < 4; ++r)
                        srow[t][r] += fast_exp2(acc[r]);
                }
            }
        __syncthreads();   // prefetched tile landed; current buffer reusable
    }

    // ---- reduction: 16 lanes sharing a row -> cross-wave (wc) via LDS
    #pragma unroll
    for (int t = 0; t < 2; ++t)
        #pragma unroll
        for (int r = 0; r < 4; ++r) {
            float v = srow[t][r];
            v += __shfl_xor(v, 1);
            v += __shfl_xor(v, 2);
            v += __shfl_xor(v, 4);
            v += __shfl_xor(v, 8);
            if (l15 == 0) red[wr * 32 + t * 16 + lg * 4 + r][wc] = v;
        }
    __syncthreads();
    if (tid < 128)
        s_partial[(size_t)cr * B_ROWS + R0 + tid] = red[tid][0] + red[tid][1];
}

// ---------------- Kernel 3: fused per-row loss + last-block final reduce ----
// 32 blocks. Each publishes its partial via device-scope atomicExch (atomics
// resolve at the coherence point -> no cross-XCD dirty-line-merge hazard on
// the shared part[] cache line), then release-fence + arrival counter; the
// last block acquire-fences and does the deterministic fixed-order final sum.
__global__ void k_loss(const float* __restrict__ sp,
                       const float* __restrict__ pos,
                       float* __restrict__ part,
                       unsigned* __restrict__ cnt,
                       float* __restrict__ out) {
    int i = blockIdx.x * 256 + threadIdx.x;
    float ssum = 0.f;
    #pragma unroll
    for (int c = 0; c < NSLAB; ++c) ssum += sp[(size_t)c * B_ROWS + i];
    float v = LN2 * fast_log2(ssum) - pos[i];
    #pragma unroll
    for (int m = 1; m < 64; m <<= 1) v += __shfl_xor(v, m);
    __shared__ float ls[4];
    __shared__ bool last;
    if ((threadIdx.x & 63) == 0) ls[threadIdx.x >> 6] = v;
    __syncthreads();
    if (threadIdx.x == 0) {
        atomicExch(part + blockIdx.x, ls[0] + ls[1] + ls[2] + ls[3]);
        __threadfence();                       // release: partial visible
        last = (atomicAdd(cnt, 1) == NLOSS - 1);
    }
    __syncthreads();
    if (last && threadIdx.x < 64) {
        __threadfence();                       // acquire: drop stale cache
        float f = (threadIdx.x < NLOSS) ? part[threadIdx.x] : 0.f;
        #pragma unroll
        for (int m = 1; m < 64; m <<= 1) f += __shfl_xor(f, m);
        if (threadIdx.x == 0) out[0] = f * (1.0f / (float)B_ROWS);
    }
}

extern "C" void kernel_launch(void* const* d_in, const int* in_sizes, int n_in,
                              void* d_out, int out_size, void* d_ws, size_t ws_size,
                              hipStream_t stream) {
    const float* z = (const float*)d_in[0];
    float* out = (float*)d_out;

    char* ws = (char*)d_ws;
    uint8_t* zn8 = (uint8_t*)ws;                                           // 1 MB
    float* s_partial = (float*)(ws + (size_t)B_ROWS * D_DIM);              // 256 KB
    float* pos  = (float*)((char*)s_partial + (size_t)NSLAB * B_ROWS * 4); // 32 KB
    float* part = (float*)((char*)pos + (size_t)B_ROWS * 4);               // 128 B
    unsigned* cnt = (unsigned*)((char*)part + NLOSS * 4);                  // 4 B

    // 1) normalize + scale + fp8 quantize (+ counter reset)
    k_norm<<<B_ROWS / 4, 256, 0, stream>>>(z, zn8, cnt);

    // 2) fp8 similarity: 64 row-tiles x 8 col-ranges = 512 blocks (2/CU)
    k_sim<<<64 * NSLAB, 512, 0, stream>>>(zn8, s_partial, pos);

    // 3) fused per-row loss + final reduce (last block)
    k_loss<<<NLOSS, 256, 0, stream>>>(s_partial, pos, part, cnt, out);
}